// Round 3
// baseline (249.434 us; speedup 1.0000x reference)
//
#include <hip/hip_runtime.h>
#include <hip/hip_bf16.h>

#define D_DIM 768
#define HS 64
#define SEQ 4096
#define NBATCH 8

typedef short bf8 __attribute__((ext_vector_type(8)));   // 8 bf16 (4 VGPR) MFMA A/B frag
typedef short bf4 __attribute__((ext_vector_type(4)));   // 4 bf16 (8 B)
typedef float f4 __attribute__((ext_vector_type(4)));    // MFMA C/D frag

static __device__ __forceinline__ short f2b(float x) {
    __hip_bfloat16 h = __float2bfloat16(x);
    return __builtin_bit_cast(short, h);
}
// pack two fp32 -> bf16x2 dword (round-half-up): 2 add + 1 v_perm
static __device__ __forceinline__ unsigned pk2(float x, float y) {
    unsigned ux = __builtin_bit_cast(unsigned, x) + 0x8000u;
    unsigned uy = __builtin_bit_cast(unsigned, y) + 0x8000u;
    return __builtin_amdgcn_perm(uy, ux, 0x07060302u);  // {uy[3],uy[2],ux[3],ux[2]}
}

#if defined(__has_builtin)
#if __has_builtin(__builtin_amdgcn_exp2f)
#define EXP2F(x) __builtin_amdgcn_exp2f(x)
#endif
#endif
#ifndef EXP2F
#define EXP2F(x) exp2f(x)
#endif

// ---------------------------------------------------------------------------
// Kernel 0: W[768][64] fp32 x3 -> Wt[c=mat*64+n][k] bf16; softmax scale *
// log2(e) baked into Wq so attention scores feed exp2 directly.
// ---------------------------------------------------------------------------
__global__ __launch_bounds__(256) void wconv_kernel(
    const float* __restrict__ Wk, const float* __restrict__ Wq,
    const float* __restrict__ Wv, short* __restrict__ wt)
{
    int tid = blockIdx.x * 256 + threadIdx.x;
    int mat = tid / (D_DIM * HS);
    int rem = tid - mat * (D_DIM * HS);
    int k = rem >> 6;
    int n = rem & 63;
    const float* W = (mat == 0) ? Wk : (mat == 1) ? Wq : Wv;
    float scale = (mat == 1) ? 0.18033688011112042f : 1.0f;  // log2(e)/8
    wt[(mat * HS + n) * D_DIM + k] = f2b(W[rem] * scale);
}

// ---------------------------------------------------------------------------
// Kernel 1: projections. [32768 x 768] @ [768 x 192] -> q,k,v bf16 [B*S][64].
// M=32 tiles -> 1024 blocks = 4 blocks/CU (was grid-capped at 2). Wave w
// handles 48 cols (3 n-frags) x 32 rows (2 m-frags). K chunks of 32, dbuf LDS.
// ---------------------------------------------------------------------------
__global__ __launch_bounds__(256) void proj_kernel(
    const float* __restrict__ ix, const short* __restrict__ wt,
    short* __restrict__ qg, short* __restrict__ kg, short* __restrict__ vg)
{
    __shared__ short ixl[2][32 * 40];    // [row][k 0..32), stride 40
    __shared__ short wtl[2][192 * 40];   // [c][k 0..32), stride 40

    const int t = threadIdx.x;
    const int wave = t >> 6, lane = t & 63;
    const int m = lane & 15, quad = lane >> 4;
    const int m0 = blockIdx.x * 32;

    const int srow = t >> 3;           // ix staging: row 0..31
    const int skoff = (t & 7) * 4;     // k offset 0,4,..,28 (floats)

    f4 xr;
    bf8 wr0, wr1, wr2, wr3;

    auto load_chunk = [&](int c) {
        const float* px = ix + (m0 + srow) * D_DIM + c * 32 + skoff;
        xr = *(const f4*)px;
        if (t < 192) {
            const short* pw = wt + t * D_DIM + c * 32;
            wr0 = *(const bf8*)(pw);
            wr1 = *(const bf8*)(pw + 8);
            wr2 = *(const bf8*)(pw + 16);
            wr3 = *(const bf8*)(pw + 24);
        }
    };
    auto write_chunk = [&](int p) {
        bf4 xw;
        #pragma unroll
        for (int i = 0; i < 4; ++i) xw[i] = f2b(xr[i]);
        *(bf4*)(&ixl[p][srow * 40 + skoff]) = xw;
        if (t < 192) {
            *(bf8*)(&wtl[p][t * 40 + 0])  = wr0;
            *(bf8*)(&wtl[p][t * 40 + 8])  = wr1;
            *(bf8*)(&wtl[p][t * 40 + 16]) = wr2;
            *(bf8*)(&wtl[p][t * 40 + 24]) = wr3;
        }
    };

    f4 acc[2][3] = {};

    load_chunk(0); write_chunk(0); __syncthreads();

    for (int c = 0; c < 24; ++c) {
        const int p = c & 1;
        if (c + 1 < 24) load_chunk(c + 1);

        bf8 a0 = *(const bf8*)(&ixl[p][(m) * 40 + quad * 8]);
        bf8 a1 = *(const bf8*)(&ixl[p][(16 + m) * 40 + quad * 8]);
        bf8 bb[3];
        #pragma unroll
        for (int nt = 0; nt < 3; ++nt)
            bb[nt] = *(const bf8*)(&wtl[p][(wave * 48 + nt * 16 + m) * 40 + quad * 8]);
        #pragma unroll
        for (int nt = 0; nt < 3; ++nt) {
            acc[0][nt] = __builtin_amdgcn_mfma_f32_16x16x32_bf16(a0, bb[nt], acc[0][nt], 0, 0, 0);
            acc[1][nt] = __builtin_amdgcn_mfma_f32_16x16x32_bf16(a1, bb[nt], acc[1][nt], 0, 0, 0);
        }

        if (c + 1 < 24) { write_chunk((c + 1) & 1); __syncthreads(); }
    }

    // epilogue: C/D frag row = quad*4+r, col = lane&15
    #pragma unroll
    for (int mt = 0; mt < 2; ++mt) {
        const int row = m0 + mt * 16 + quad * 4;
        #pragma unroll
        for (int nt = 0; nt < 3; ++nt) {
            const int cb = wave * 48 + nt * 16;
            short* op = (cb < 64) ? kg : (cb < 128) ? qg : vg;  // d_in order: Wk,Wq,Wv
            const int n = (cb & 63) + m;
            #pragma unroll
            for (int r = 0; r < 4; ++r)
                op[(row + r) * HS + n] = f2b(acc[mt][nt][r]);
        }
    }
}

// ---------------------------------------------------------------------------
// Kernel 2: fused attention, 4-way key split. 1024 blocks = 4 blocks/CU.
// Logical block = (qx 0..31, ks 0..3, b 0..7); XCD swizzle pins batch b to
// XCD b (q+k+v per batch = 3 MB < 4 MB per-XCD L2).
// Per block: 128 queries (4 waves x 32) x 1024 keys (16 chunks of 64).
// LDS (double-buffered):
//   kl[j][d] stride 72: K rows, A-frags for S^T = K.Q^T (16x16x32).
//   vl: V^T, stride 64 shorts, XOR-swizzled 16B chunks:
//     element (d, j) with j=(gj,q,h,r) [j = 32gj+16h+4q+r] lives at logical
//     short col 32gj + 8q + 4h + r; phys chunk = logical chunk ^ (d&7)^(d>>3).
//     Writes: paired-row b32 (4-way conflict, ~2 extra cy); reads: one
//     aligned b128 per (dt,g) with provably uniform banks (0 conflict).
// pf trick: concat of the two 16-row S^T C-frags post exp+pack is per-lane a
// valid 16x16x32 B-frag under row-perm pi; vl's column encoding bakes pi in.
// ---------------------------------------------------------------------------
__global__ __launch_bounds__(256, 4) void attn_kernel(
    const short* __restrict__ qg, const short* __restrict__ kg,
    const short* __restrict__ vg, float* __restrict__ num0,
    float* __restrict__ num1, float* __restrict__ num2,
    float* __restrict__ num3, float* __restrict__ den0,
    float* __restrict__ den1, float* __restrict__ den2,
    float* __restrict__ den3)
{
    __shared__ short kl[2][64 * 72];
    __shared__ short vl[2][64 * 64];

    const int t = threadIdx.x;
    const int wave = t >> 6, lane = t & 63;
    const int m = lane & 15, quad = lane >> 4;

    // XCD-aware remap: batch = XCD index
    const int flat = blockIdx.x;
    const int lg = (flat & 7) * 128 + (flat >> 3);
    const int qx = lg & 31;
    const int ks = (lg >> 5) & 3;
    const int b  = lg >> 7;

    const int rbase = b * SEQ;
    const int kbase = rbase + ks * (SEQ / 4);
    const int qw = qx * 128 + wave * 32;

    float* __restrict__ nump = (ks == 0) ? num0 : (ks == 1) ? num1 : (ks == 2) ? num2 : num3;
    float* __restrict__ denp = (ks == 0) ? den0 : (ks == 1) ? den1 : (ks == 2) ? den2 : den3;

    // persistent Q B-frags: lane n=q=lane&15, k=d=quad*8+e (+32 per step)
    bf8 qf[2][2];
    #pragma unroll
    for (int nq = 0; nq < 2; ++nq)
        #pragma unroll
        for (int st = 0; st < 2; ++st)
            qf[nq][st] = *(const bf8*)(qg + (rbase + qw + nq * 16 + m) * HS + st * 32 + quad * 8);

    // K staging: row srow, 32B of d per thread
    const int srow = t >> 2, soff = (t & 3) * 16;
    // V staging: row-pair j0 = 2*jp, 8 d's per thread
    const int jp = t >> 3, dg = t & 7;
    const int j0 = jp * 2;
    const int jj = j0 & 31;
    const int gj = j0 >> 5;
    const int vq = (jj >> 2) & 3;          // q bits of j0
    const int vh = (jj >> 4) & 1;          // h bit
    const int vb = (jj & 3) >> 1;          // r = 2*vb
    const int vcol_base = vh * 4 + 2 * vb; // within-chunk short offset
    const int vchunk_l = 4 * gj + vq;      // logical 16B chunk

    uint4 kr0, kr1, vr0, vr1;
    auto load_chunk = [&](int c) {
        const short* pk = kg + (kbase + c * 64 + srow) * HS + soff;
        kr0 = *(const uint4*)pk; kr1 = *(const uint4*)(pk + 8);
        const short* pv = vg + (kbase + c * 64 + j0) * HS + dg * 8;
        vr0 = *(const uint4*)pv; vr1 = *(const uint4*)(pv + HS);
    };
    auto write_chunk = [&](int p) {
        *(bf8*)(&kl[p][srow * 72 + soff])     = __builtin_bit_cast(bf8, kr0);
        *(bf8*)(&kl[p][srow * 72 + soff + 8]) = __builtin_bit_cast(bf8, kr1);
        bf8 v0 = __builtin_bit_cast(bf8, vr0), v1 = __builtin_bit_cast(bf8, vr1);
        #pragma unroll
        for (int i = 0; i < 8; ++i) {
            const int d = dg * 8 + i;
            const int chunk = vchunk_l ^ (i ^ dg);     // (d&7)^(d>>3) = i^dg
            unsigned val = (unsigned short)v0[i] | ((unsigned)(unsigned short)v1[i] << 16);
            *(unsigned*)(&vl[p][d * 64 + chunk * 8 + vcol_base]) = val;
        }
    };

    f4 o[2][4] = {};
    float den[2] = {0.f, 0.f};

    load_chunk(0); write_chunk(0); __syncthreads();

    const int NCH = SEQ / 4 / 64;   // 16 chunks of 64 keys
    for (int c = 0; c < NCH; ++c) {
        const int p = c & 1;
        if (c + 1 < NCH) load_chunk(c + 1);

        #pragma unroll
        for (int g = 0; g < 2; ++g) {       // 32-key groups
            // K A-frags (16x16x32): rows g*32+m and g*32+16+m
            bf8 kA0 = *(const bf8*)(&kl[p][(g * 32 + m) * 72 + quad * 8]);
            bf8 kA1 = *(const bf8*)(&kl[p][(g * 32 + m) * 72 + 32 + quad * 8]);
            bf8 kB0 = *(const bf8*)(&kl[p][(g * 32 + 16 + m) * 72 + quad * 8]);
            bf8 kB1 = *(const bf8*)(&kl[p][(g * 32 + 16 + m) * 72 + 32 + quad * 8]);

            // V^T A-frags: one aligned b128 each, XOR-swizzled (0 conflicts)
            bf8 vf[4];
            #pragma unroll
            for (int dt = 0; dt < 4; ++dt) {
                const int row = dt * 16 + m;
                const int key = (m & 7) ^ (2 * dt + (m >> 3));   // (d&7)^(d>>3)
                const int chunk = (g * 4 + quad) ^ key;
                vf[dt] = *(const bf8*)(&vl[p][row * 64 + chunk * 8]);
            }

            #pragma unroll
            for (int nq = 0; nq < 2; ++nq) {
                f4 sa = {0.f, 0.f, 0.f, 0.f}, sb = {0.f, 0.f, 0.f, 0.f};
                sa = __builtin_amdgcn_mfma_f32_16x16x32_bf16(kA0, qf[nq][0], sa, 0, 0, 0);
                sa = __builtin_amdgcn_mfma_f32_16x16x32_bf16(kA1, qf[nq][1], sa, 0, 0, 0);
                sb = __builtin_amdgcn_mfma_f32_16x16x32_bf16(kB0, qf[nq][0], sb, 0, 0, 0);
                sb = __builtin_amdgcn_mfma_f32_16x16x32_bf16(kB1, qf[nq][1], sb, 0, 0, 0);
                float e0 = EXP2F(sa[0]), e1 = EXP2F(sa[1]), e2 = EXP2F(sa[2]), e3 = EXP2F(sa[3]);
                float e4 = EXP2F(sb[0]), e5 = EXP2F(sb[1]), e6 = EXP2F(sb[2]), e7 = EXP2F(sb[3]);
                den[nq] += ((e0 + e1) + (e2 + e3)) + ((e4 + e5) + (e6 + e7));
                uint4 pu;
                pu.x = pk2(e0, e1); pu.y = pk2(e2, e3);
                pu.z = pk2(e4, e5); pu.w = pk2(e6, e7);
                bf8 pf = __builtin_bit_cast(bf8, pu);
                #pragma unroll
                for (int dt = 0; dt < 4; ++dt)
                    o[nq][dt] = __builtin_amdgcn_mfma_f32_16x16x32_bf16(vf[dt], pf, o[nq][dt], 0, 0, 0);
            }
        }

        if (c + 1 < NCH) { write_chunk((c + 1) & 1); __syncthreads(); }
    }

    // epilogue: O^T frag row=d=dt*16+quad*4+r, col=q=lane&15. Partial sums out.
    #pragma unroll
    for (int nq = 0; nq < 2; ++nq) {
        float d = den[nq];
        d += __shfl_xor(d, 16, 64);
        d += __shfl_xor(d, 32, 64);
        const int orow = rbase + qw + nq * 16 + m;
        if (quad == 0) denp[orow] = d;
        #pragma unroll
        for (int dt = 0; dt < 4; ++dt)
            *(f4*)(nump + orow * HS + dt * 16 + quad * 4) = o[nq][dt];
    }
}

// ---------------------------------------------------------------------------
// Kernel 3: combine the four key-splits: out = sum(num_i)/sum(den_i).
// num0 lives in d_out (in-place).
// ---------------------------------------------------------------------------
__global__ __launch_bounds__(256) void reduce_kernel(
    float* __restrict__ out, const float* __restrict__ num1,
    const float* __restrict__ num2, const float* __restrict__ num3,
    const float* __restrict__ den0, const float* __restrict__ den1,
    const float* __restrict__ den2, const float* __restrict__ den3)
{
    const int gid = blockIdx.x * 256 + threadIdx.x;
    const int base = gid * 4;
    const int r = base >> 6;
    f4 n0 = *(const f4*)(out + base);
    f4 n1 = *(const f4*)(num1 + base);
    f4 n2 = *(const f4*)(num2 + base);
    f4 n3 = *(const f4*)(num3 + base);
    const float rs = 1.0f / ((den0[r] + den1[r]) + (den2[r] + den3[r]));
    f4 res;
    #pragma unroll
    for (int i = 0; i < 4; ++i) res[i] = ((n0[i] + n1[i]) + (n2[i] + n3[i])) * rs;
    *(f4*)(out + base) = res;
}

extern "C" void kernel_launch(void* const* d_in, const int* in_sizes, int n_in,
                              void* d_out, int out_size, void* d_ws, size_t ws_size,
                              hipStream_t stream) {
    const float* ix = (const float*)d_in[0];
    const float* Wk = (const float*)d_in[1];
    const float* Wq = (const float*)d_in[2];
    const float* Wv = (const float*)d_in[3];
    float* out = (float*)d_out;

    const size_t NQKV = (size_t)NBATCH * SEQ * HS;      // 2,097,152 elements
    short* qg = (short*)d_ws;
    short* kg = qg + NQKV;
    short* vg = kg + NQKV;
    short* wt = vg + NQKV;                              // 192*768 shorts
    char*  fbase = (char*)(wt + 3 * D_DIM * HS);        // 16B-aligned
    float* num1 = (float*)fbase;
    float* num2 = num1 + NQKV;
    float* num3 = num2 + NQKV;
    float* den0 = num3 + NQKV;
    float* den1 = den0 + (size_t)NBATCH * SEQ;
    float* den2 = den1 + (size_t)NBATCH * SEQ;
    float* den3 = den2 + (size_t)NBATCH * SEQ;
    // total ws use ~38.6 MB

    wconv_kernel<<<(3 * D_DIM * HS) / 256, 256, 0, stream>>>(Wk, Wq, Wv, wt);
    proj_kernel<<<(NBATCH * SEQ) / 32, 256, 0, stream>>>(ix, wt, qg, kg, vg);
    attn_kernel<<<1024, 256, 0, stream>>>(qg, kg, vg, out, num1, num2, num3,
                                          den0, den1, den2, den3);
    reduce_kernel<<<(int)(NQKV / (256 * 4)), 256, 0, stream>>>(
        out, num1, num2, num3, den0, den1, den2, den3);
}

// Round 4
// 219.733 us; speedup vs baseline: 1.1352x; 1.1352x over previous
//
#include <hip/hip_runtime.h>
#include <hip/hip_bf16.h>

#define D_DIM 768
#define HS 64
#define SEQ 4096
#define NBATCH 8

typedef short bf8 __attribute__((ext_vector_type(8)));   // 8 bf16 (4 VGPR) MFMA A/B frag
typedef short bf4 __attribute__((ext_vector_type(4)));   // 4 bf16 (8 B)
typedef float f4 __attribute__((ext_vector_type(4)));    // MFMA C/D frag

static __device__ __forceinline__ short f2b(float x) {
    __hip_bfloat16 h = __float2bfloat16(x);
    return __builtin_bit_cast(short, h);
}
// pack two fp32 -> bf16x2 dword (round-half-up): 2 add + 1 v_perm
static __device__ __forceinline__ unsigned pk2(float x, float y) {
    unsigned ux = __builtin_bit_cast(unsigned, x) + 0x8000u;
    unsigned uy = __builtin_bit_cast(unsigned, y) + 0x8000u;
    return __builtin_amdgcn_perm(uy, ux, 0x07060302u);  // {uy[3],uy[2],ux[3],ux[2]}
}

#if defined(__has_builtin)
#if __has_builtin(__builtin_amdgcn_exp2f)
#define EXP2F(x) __builtin_amdgcn_exp2f(x)
#endif
#endif
#ifndef EXP2F
#define EXP2F(x) exp2f(x)
#endif

// ---------------------------------------------------------------------------
// Kernel 0: W[768][64] fp32 x3 -> wt3 in MFMA-fragment-direct order:
//   wt3[(c32*192 + col)*32 + quad*8 + e] = W[k][n],  col = mat*64+n,
//   k = c32*32 + quad*8 + e.  A proj B-frag load (16 cols x 4 quads) is then
//   ONE contiguous 1 KB global_load_dwordx4 per wave — fully coalesced.
// Softmax scale * log2(e) baked into Wq so scores feed exp2 directly.
// ---------------------------------------------------------------------------
__global__ __launch_bounds__(256) void wconv_kernel(
    const float* __restrict__ Wk, const float* __restrict__ Wq,
    const float* __restrict__ Wv, short* __restrict__ wt3)
{
    int tid = blockIdx.x * 256 + threadIdx.x;
    int mat = tid / (D_DIM * HS);
    int rem = tid - mat * (D_DIM * HS);
    int k = rem >> 6;
    int n = rem & 63;
    const float* W = (mat == 0) ? Wk : (mat == 1) ? Wq : Wv;
    float scale = (mat == 1) ? 0.18033688011112042f : 1.0f;  // log2(e)/8
    int cc = mat * HS + n;
    int c = k >> 5, q = (k >> 3) & 3, e = k & 7;
    wt3[(c * 192 + cc) * 32 + q * 8 + e] = f2b(W[rem] * scale);
}

// ---------------------------------------------------------------------------
// Kernel 1: projections. [32768 x 768] @ [768 x 192] -> q,k,v bf16 [B*S][64].
// 1024 blocks (4/CU) x 256 thr. Block: 32-row M-tile; wave w: 48 cols.
// Weights: NO LDS — direct fragment loads from wt3 (one coalesced 1 KB b128
// per frag, L2-resident). ix: LDS double-buffer, K-chunk=64, stride 72.
// (R3's wt staging was a 64-cache-line split per load -> latency-bound 82 us,
//  all pipes <5%.)
// ---------------------------------------------------------------------------
__global__ __launch_bounds__(256) void proj_kernel(
    const float* __restrict__ ix, const short* __restrict__ wt3,
    short* __restrict__ qg, short* __restrict__ kg, short* __restrict__ vg)
{
    __shared__ short ixl[2][32 * 72];   // [row][k 0..64), stride 72

    const int t = threadIdx.x;
    const int wave = t >> 6, lane = t & 63;
    const int m = lane & 15, quad = lane >> 4;
    const int m0 = blockIdx.x * 32;

    const int srow = t >> 3;          // ix staging: row 0..31
    const int skoff = (t & 7) * 8;    // float col 0,8,..,56

    f4 xr0, xr1;
    auto load_ix = [&](int c) {
        const float* px = ix + (m0 + srow) * D_DIM + c * 64 + skoff;
        xr0 = *(const f4*)px;
        xr1 = *(const f4*)(px + 4);
    };
    auto write_ix = [&](int p) {
        bf8 xw;
        #pragma unroll
        for (int i = 0; i < 4; ++i) { xw[i] = f2b(xr0[i]); xw[i + 4] = f2b(xr1[i]); }
        *(bf8*)(&ixl[p][srow * 72 + skoff]) = xw;
    };

    const int colb = wave * 48;
    f4 acc[2][3] = {};

    load_ix(0); write_ix(0); __syncthreads();

    for (int c = 0; c < 12; ++c) {      // 64-k chunks
        const int p = c & 1;
        if (c + 1 < 12) load_ix(c + 1);

        // B-frags direct from global (fragment-ordered): halves 2c, 2c+1
        bf8 b0[3], b1[3];
        #pragma unroll
        for (int nt = 0; nt < 3; ++nt) {
            const short* pw = wt3 + ((2 * c) * 192 + colb + nt * 16 + m) * 32 + quad * 8;
            b0[nt] = *(const bf8*)pw;
            b1[nt] = *(const bf8*)(pw + 192 * 32);
        }
        // A-frags from LDS
        bf8 a0 = *(const bf8*)(&ixl[p][m * 72 + quad * 8]);
        bf8 a1 = *(const bf8*)(&ixl[p][m * 72 + 32 + quad * 8]);
        bf8 a2 = *(const bf8*)(&ixl[p][(16 + m) * 72 + quad * 8]);
        bf8 a3 = *(const bf8*)(&ixl[p][(16 + m) * 72 + 32 + quad * 8]);

        #pragma unroll
        for (int nt = 0; nt < 3; ++nt) {
            acc[0][nt] = __builtin_amdgcn_mfma_f32_16x16x32_bf16(a0, b0[nt], acc[0][nt], 0, 0, 0);
            acc[0][nt] = __builtin_amdgcn_mfma_f32_16x16x32_bf16(a1, b1[nt], acc[0][nt], 0, 0, 0);
            acc[1][nt] = __builtin_amdgcn_mfma_f32_16x16x32_bf16(a2, b0[nt], acc[1][nt], 0, 0, 0);
            acc[1][nt] = __builtin_amdgcn_mfma_f32_16x16x32_bf16(a3, b1[nt], acc[1][nt], 0, 0, 0);
        }

        if (c + 1 < 12) { write_ix((c + 1) & 1); __syncthreads(); }
    }

    // epilogue: C/D frag row = quad*4+r (ix row), col = lane&15 (wt col)
    #pragma unroll
    for (int mt = 0; mt < 2; ++mt) {
        const int row = m0 + mt * 16 + quad * 4;
        #pragma unroll
        for (int nt = 0; nt < 3; ++nt) {
            const int cb = colb + nt * 16;
            short* op = (cb < 64) ? kg : (cb < 128) ? qg : vg;  // d_in order: Wk,Wq,Wv
            const int n = (cb & 63) + m;
            #pragma unroll
            for (int r = 0; r < 4; ++r)
                op[(row + r) * HS + n] = f2b(acc[mt][nt][r]);
        }
    }
}

// ---------------------------------------------------------------------------
// Kernel 2: fused attention, 4-way key split. 1024 blocks = 4 blocks/CU.
// (unchanged from R3 — counters for it were hidden this round)
// ---------------------------------------------------------------------------
__global__ __launch_bounds__(256, 4) void attn_kernel(
    const short* __restrict__ qg, const short* __restrict__ kg,
    const short* __restrict__ vg, float* __restrict__ num0,
    float* __restrict__ num1, float* __restrict__ num2,
    float* __restrict__ num3, float* __restrict__ den0,
    float* __restrict__ den1, float* __restrict__ den2,
    float* __restrict__ den3)
{
    __shared__ short kl[2][64 * 72];
    __shared__ short vl[2][64 * 64];

    const int t = threadIdx.x;
    const int wave = t >> 6, lane = t & 63;
    const int m = lane & 15, quad = lane >> 4;

    // XCD-aware remap: batch = XCD index
    const int flat = blockIdx.x;
    const int lg = (flat & 7) * 128 + (flat >> 3);
    const int qx = lg & 31;
    const int ks = (lg >> 5) & 3;
    const int b  = lg >> 7;

    const int rbase = b * SEQ;
    const int kbase = rbase + ks * (SEQ / 4);
    const int qw = qx * 128 + wave * 32;

    float* __restrict__ nump = (ks == 0) ? num0 : (ks == 1) ? num1 : (ks == 2) ? num2 : num3;
    float* __restrict__ denp = (ks == 0) ? den0 : (ks == 1) ? den1 : (ks == 2) ? den2 : den3;

    // persistent Q B-frags: lane n=q=lane&15, k=d=quad*8+e (+32 per step)
    bf8 qf[2][2];
    #pragma unroll
    for (int nq = 0; nq < 2; ++nq)
        #pragma unroll
        for (int st = 0; st < 2; ++st)
            qf[nq][st] = *(const bf8*)(qg + (rbase + qw + nq * 16 + m) * HS + st * 32 + quad * 8);

    // K staging: row srow, 32B of d per thread
    const int srow = t >> 2, soff = (t & 3) * 16;
    // V staging: row-pair j0 = 2*jp, 8 d's per thread
    const int jp = t >> 3, dg = t & 7;
    const int j0 = jp * 2;
    const int jj = j0 & 31;
    const int gj = j0 >> 5;
    const int vq = (jj >> 2) & 3;
    const int vh = (jj >> 4) & 1;
    const int vb = (jj & 3) >> 1;
    const int vcol_base = vh * 4 + 2 * vb;
    const int vchunk_l = 4 * gj + vq;

    uint4 kr0, kr1, vr0, vr1;
    auto load_chunk = [&](int c) {
        const short* pk = kg + (kbase + c * 64 + srow) * HS + soff;
        kr0 = *(const uint4*)pk; kr1 = *(const uint4*)(pk + 8);
        const short* pv = vg + (kbase + c * 64 + j0) * HS + dg * 8;
        vr0 = *(const uint4*)pv; vr1 = *(const uint4*)(pv + HS);
    };
    auto write_chunk = [&](int p) {
        *(bf8*)(&kl[p][srow * 72 + soff])     = __builtin_bit_cast(bf8, kr0);
        *(bf8*)(&kl[p][srow * 72 + soff + 8]) = __builtin_bit_cast(bf8, kr1);
        bf8 v0 = __builtin_bit_cast(bf8, vr0), v1 = __builtin_bit_cast(bf8, vr1);
        #pragma unroll
        for (int i = 0; i < 8; ++i) {
            const int d = dg * 8 + i;
            const int chunk = vchunk_l ^ (i ^ dg);     // (d&7)^(d>>3)
            unsigned val = (unsigned short)v0[i] | ((unsigned)(unsigned short)v1[i] << 16);
            *(unsigned*)(&vl[p][d * 64 + chunk * 8 + vcol_base]) = val;
        }
    };

    f4 o[2][4] = {};
    float den[2] = {0.f, 0.f};

    load_chunk(0); write_chunk(0); __syncthreads();

    const int NCH = SEQ / 4 / 64;   // 16 chunks of 64 keys
    for (int c = 0; c < NCH; ++c) {
        const int p = c & 1;
        if (c + 1 < NCH) load_chunk(c + 1);

        #pragma unroll
        for (int g = 0; g < 2; ++g) {
            bf8 kA0 = *(const bf8*)(&kl[p][(g * 32 + m) * 72 + quad * 8]);
            bf8 kA1 = *(const bf8*)(&kl[p][(g * 32 + m) * 72 + 32 + quad * 8]);
            bf8 kB0 = *(const bf8*)(&kl[p][(g * 32 + 16 + m) * 72 + quad * 8]);
            bf8 kB1 = *(const bf8*)(&kl[p][(g * 32 + 16 + m) * 72 + 32 + quad * 8]);

            bf8 vf[4];
            #pragma unroll
            for (int dt = 0; dt < 4; ++dt) {
                const int row = dt * 16 + m;
                const int key = (m & 7) ^ (2 * dt + (m >> 3));
                const int chunk = (g * 4 + quad) ^ key;
                vf[dt] = *(const bf8*)(&vl[p][row * 64 + chunk * 8]);
            }

            #pragma unroll
            for (int nq = 0; nq < 2; ++nq) {
                f4 sa = {0.f, 0.f, 0.f, 0.f}, sb = {0.f, 0.f, 0.f, 0.f};
                sa = __builtin_amdgcn_mfma_f32_16x16x32_bf16(kA0, qf[nq][0], sa, 0, 0, 0);
                sa = __builtin_amdgcn_mfma_f32_16x16x32_bf16(kA1, qf[nq][1], sa, 0, 0, 0);
                sb = __builtin_amdgcn_mfma_f32_16x16x32_bf16(kB0, qf[nq][0], sb, 0, 0, 0);
                sb = __builtin_amdgcn_mfma_f32_16x16x32_bf16(kB1, qf[nq][1], sb, 0, 0, 0);
                float e0 = EXP2F(sa[0]), e1 = EXP2F(sa[1]), e2 = EXP2F(sa[2]), e3 = EXP2F(sa[3]);
                float e4 = EXP2F(sb[0]), e5 = EXP2F(sb[1]), e6 = EXP2F(sb[2]), e7 = EXP2F(sb[3]);
                den[nq] += ((e0 + e1) + (e2 + e3)) + ((e4 + e5) + (e6 + e7));
                uint4 pu;
                pu.x = pk2(e0, e1); pu.y = pk2(e2, e3);
                pu.z = pk2(e4, e5); pu.w = pk2(e6, e7);
                bf8 pf = __builtin_bit_cast(bf8, pu);
                #pragma unroll
                for (int dt = 0; dt < 4; ++dt)
                    o[nq][dt] = __builtin_amdgcn_mfma_f32_16x16x32_bf16(vf[dt], pf, o[nq][dt], 0, 0, 0);
            }
        }

        if (c + 1 < NCH) { write_chunk((c + 1) & 1); __syncthreads(); }
    }

    #pragma unroll
    for (int nq = 0; nq < 2; ++nq) {
        float d = den[nq];
        d += __shfl_xor(d, 16, 64);
        d += __shfl_xor(d, 32, 64);
        const int orow = rbase + qw + nq * 16 + m;
        if (quad == 0) denp[orow] = d;
        #pragma unroll
        for (int dt = 0; dt < 4; ++dt)
            *(f4*)(nump + orow * HS + dt * 16 + quad * 4) = o[nq][dt];
    }
}

// ---------------------------------------------------------------------------
// Kernel 3: combine the four key-splits: out = sum(num_i)/sum(den_i).
// ---------------------------------------------------------------------------
__global__ __launch_bounds__(256) void reduce_kernel(
    float* __restrict__ out, const float* __restrict__ num1,
    const float* __restrict__ num2, const float* __restrict__ num3,
    const float* __restrict__ den0, const float* __restrict__ den1,
    const float* __restrict__ den2, const float* __restrict__ den3)
{
    const int gid = blockIdx.x * 256 + threadIdx.x;
    const int base = gid * 4;
    const int r = base >> 6;
    f4 n0 = *(const f4*)(out + base);
    f4 n1 = *(const f4*)(num1 + base);
    f4 n2 = *(const f4*)(num2 + base);
    f4 n3 = *(const f4*)(num3 + base);
    const float rs = 1.0f / ((den0[r] + den1[r]) + (den2[r] + den3[r]));
    f4 res;
    #pragma unroll
    for (int i = 0; i < 4; ++i) res[i] = ((n0[i] + n1[i]) + (n2[i] + n3[i])) * rs;
    *(f4*)(out + base) = res;
}

extern "C" void kernel_launch(void* const* d_in, const int* in_sizes, int n_in,
                              void* d_out, int out_size, void* d_ws, size_t ws_size,
                              hipStream_t stream) {
    const float* ix = (const float*)d_in[0];
    const float* Wk = (const float*)d_in[1];
    const float* Wq = (const float*)d_in[2];
    const float* Wv = (const float*)d_in[3];
    float* out = (float*)d_out;

    const size_t NQKV = (size_t)NBATCH * SEQ * HS;      // 2,097,152 elements
    short* qg = (short*)d_ws;
    short* kg = qg + NQKV;
    short* vg = kg + NQKV;
    short* wt3 = vg + NQKV;                             // 24*192*32 = 147456 shorts
    char*  fbase = (char*)(wt3 + 24 * 192 * 32);        // 16B-aligned
    float* num1 = (float*)fbase;
    float* num2 = num1 + NQKV;
    float* num3 = num2 + NQKV;
    float* den0 = num3 + NQKV;
    float* den1 = den0 + (size_t)NBATCH * SEQ;
    float* den2 = den1 + (size_t)NBATCH * SEQ;
    float* den3 = den2 + (size_t)NBATCH * SEQ;

    wconv_kernel<<<(3 * D_DIM * HS) / 256, 256, 0, stream>>>(Wk, Wq, Wv, wt3);
    proj_kernel<<<(NBATCH * SEQ) / 32, 256, 0, stream>>>(ix, wt3, qg, kg, vg);
    attn_kernel<<<1024, 256, 0, stream>>>(qg, kg, vg, out, num1, num2, num3,
                                          den0, den1, den2, den3);
    reduce_kernel<<<(int)(NQKV / (256 * 4)), 256, 0, stream>>>(
        out, num1, num2, num3, den0, den1, den2, den3);
}

// Round 5
// 216.842 us; speedup vs baseline: 1.1503x; 1.0133x over previous
//
#include <hip/hip_runtime.h>
#include <hip/hip_bf16.h>

#define D_DIM 768
#define HS 64
#define SEQ 4096
#define NBATCH 8

typedef short bf8 __attribute__((ext_vector_type(8)));   // 8 bf16 (4 VGPR) MFMA A/B frag
typedef short bf4 __attribute__((ext_vector_type(4)));   // 4 bf16 (8 B)
typedef float f4 __attribute__((ext_vector_type(4)));    // MFMA C/D frag

static __device__ __forceinline__ short f2b(float x) {
    __hip_bfloat16 h = __float2bfloat16(x);
    return __builtin_bit_cast(short, h);
}
// pack two fp32 -> bf16x2 dword (round-half-up): 2 add + 1 v_perm
static __device__ __forceinline__ unsigned pk2(float x, float y) {
    unsigned ux = __builtin_bit_cast(unsigned, x) + 0x8000u;
    unsigned uy = __builtin_bit_cast(unsigned, y) + 0x8000u;
    return __builtin_amdgcn_perm(uy, ux, 0x07060302u);  // {uy[3],uy[2],ux[3],ux[2]}
}

#if defined(__has_builtin)
#if __has_builtin(__builtin_amdgcn_exp2f)
#define EXP2F(x) __builtin_amdgcn_exp2f(x)
#endif
#endif
#ifndef EXP2F
#define EXP2F(x) exp2f(x)
#endif

// ---------------------------------------------------------------------------
// Kernel 0: W[768][64] fp32 x3 -> wt3 in MFMA-fragment-direct order:
//   wt3[(c32*192 + col)*32 + quad*8 + e] = W[k][n],  col = mat*64+n,
//   k = c32*32 + quad*8 + e.  A proj B-frag load is one contiguous 1 KB
//   global_load_dwordx4 per wave. Softmax scale*log2(e) baked into Wq.
// ---------------------------------------------------------------------------
__global__ __launch_bounds__(256) void wconv_kernel(
    const float* __restrict__ Wk, const float* __restrict__ Wq,
    const float* __restrict__ Wv, short* __restrict__ wt3)
{
    int tid = blockIdx.x * 256 + threadIdx.x;
    int mat = tid / (D_DIM * HS);
    int rem = tid - mat * (D_DIM * HS);
    int k = rem >> 6;
    int n = rem & 63;
    const float* W = (mat == 0) ? Wk : (mat == 1) ? Wq : Wv;
    float scale = (mat == 1) ? 0.18033688011112042f : 1.0f;  // log2(e)/8
    int cc = mat * HS + n;
    int c = k >> 5, q = (k >> 3) & 3, e = k & 7;
    wt3[(c * 192 + cc) * 32 + q * 8 + e] = f2b(W[rem] * scale);
}

// ---------------------------------------------------------------------------
// Kernel 1: projections. [32768 x 768] @ [768 x 192] -> q,k,v bf16 [B*S][64].
// 1024 blocks x 256 thr; block = 32-row M-tile, wave = 48 cols.
// R5: wt3 fragment loads are now REGISTER double-buffered (prefetched one
// 64-k chunk ahead, alongside the ix dbuf) — R4 issued them in-loop and ate
// a naked ~200-300 cy L2 stall per chunk.
// ---------------------------------------------------------------------------
__global__ __launch_bounds__(256, 3) void proj_kernel(
    const float* __restrict__ ix, const short* __restrict__ wt3,
    short* __restrict__ qg, short* __restrict__ kg, short* __restrict__ vg)
{
    __shared__ short ixl[2][32 * 72];   // [row][k 0..64), stride 72

    const int t = threadIdx.x;
    const int wave = t >> 6, lane = t & 63;
    const int m = lane & 15, quad = lane >> 4;
    const int m0 = blockIdx.x * 32;

    const int srow = t >> 3;          // ix staging: row 0..31
    const int skoff = (t & 7) * 8;    // float col 0,8,..,56

    f4 xr0, xr1;
    auto load_ix = [&](int c) {
        const float* px = ix + (m0 + srow) * D_DIM + c * 64 + skoff;
        xr0 = *(const f4*)px;
        xr1 = *(const f4*)(px + 4);
    };
    auto write_ix = [&](int p) {
        bf8 xw;
        #pragma unroll
        for (int i = 0; i < 4; ++i) { xw[i] = f2b(xr0[i]); xw[i + 4] = f2b(xr1[i]); }
        *(bf8*)(&ixl[p][srow * 72 + skoff]) = xw;
    };

    const int colb = wave * 48;
    const short* wbase = wt3 + (colb + m) * 32 + quad * 8;

    bf8 wb[2][2][3];   // [buf][k-half][nt] — register dbuf for B-frags
    auto load_w = [&](int c, int buf) {
        #pragma unroll
        for (int nt = 0; nt < 3; ++nt) {
            const short* pw = wbase + ((size_t)(2 * c) * 192 + nt * 16) * 32;
            wb[buf][0][nt] = *(const bf8*)pw;
            wb[buf][1][nt] = *(const bf8*)(pw + 192 * 32);
        }
    };

    f4 acc[2][3] = {};

    load_ix(0); load_w(0, 0); write_ix(0); __syncthreads();

    #pragma unroll
    for (int c = 0; c < 12; ++c) {      // 64-k chunks
        const int p = c & 1;
        if (c + 1 < 12) { load_ix(c + 1); load_w(c + 1, (c + 1) & 1); }

        bf8 a0 = *(const bf8*)(&ixl[p][m * 72 + quad * 8]);
        bf8 a1 = *(const bf8*)(&ixl[p][m * 72 + 32 + quad * 8]);
        bf8 a2 = *(const bf8*)(&ixl[p][(16 + m) * 72 + quad * 8]);
        bf8 a3 = *(const bf8*)(&ixl[p][(16 + m) * 72 + 32 + quad * 8]);

        #pragma unroll
        for (int nt = 0; nt < 3; ++nt) {
            acc[0][nt] = __builtin_amdgcn_mfma_f32_16x16x32_bf16(a0, wb[p][0][nt], acc[0][nt], 0, 0, 0);
            acc[0][nt] = __builtin_amdgcn_mfma_f32_16x16x32_bf16(a1, wb[p][1][nt], acc[0][nt], 0, 0, 0);
            acc[1][nt] = __builtin_amdgcn_mfma_f32_16x16x32_bf16(a2, wb[p][0][nt], acc[1][nt], 0, 0, 0);
            acc[1][nt] = __builtin_amdgcn_mfma_f32_16x16x32_bf16(a3, wb[p][1][nt], acc[1][nt], 0, 0, 0);
        }

        if (c + 1 < 12) { write_ix((c + 1) & 1); __syncthreads(); }
    }

    // epilogue: C/D frag row = quad*4+r (ix row), col = lane&15 (wt col)
    #pragma unroll
    for (int mt = 0; mt < 2; ++mt) {
        const int row = m0 + mt * 16 + quad * 4;
        #pragma unroll
        for (int nt = 0; nt < 3; ++nt) {
            const int cb = colb + nt * 16;
            short* op = (cb < 64) ? kg : (cb < 128) ? qg : vg;  // d_in order: Wk,Wq,Wv
            const int n = (cb & 63) + m;
            #pragma unroll
            for (int r = 0; r < 4; ++r)
                op[(row + r) * HS + n] = f2b(acc[mt][nt][r]);
        }
    }
}

// ---------------------------------------------------------------------------
// Kernel 2: fused attention, 4-way key split. R5: 64 queries/WAVE (nq=4),
// block = 256 queries, grid 512 = 2 blocks/CU. Rationale: kl/vl LDS reads
// are identical across a block's waves (they differ only in queries), so the
// binding pipe — LDS read BW — is amortized over 2x the queries per read.
// LDS (double-buffered):
//   kl[j][d] stride 72: K rows, A-frags for S^T = K.Q^T (16x16x32).
//   vl: V^T, XOR-swizzled 16B chunks (conflict-free b128 reads).
// pf trick: concat of the two 16-row S^T C-frags post exp+pack is per-lane a
// valid 16x16x32 B-frag under row-perm pi; vl's column encoding bakes pi in.
// ---------------------------------------------------------------------------
__global__ __launch_bounds__(256, 2) void attn_kernel(
    const short* __restrict__ qg, const short* __restrict__ kg,
    const short* __restrict__ vg, float* __restrict__ num0,
    float* __restrict__ num1, float* __restrict__ num2,
    float* __restrict__ num3, float* __restrict__ den0,
    float* __restrict__ den1, float* __restrict__ den2,
    float* __restrict__ den3)
{
    __shared__ short kl[2][64 * 72];
    __shared__ short vl[2][64 * 64];

    const int t = threadIdx.x;
    const int wave = t >> 6, lane = t & 63;
    const int m = lane & 15, quad = lane >> 4;

    // XCD-aware remap: batch = XCD index (512 blocks, 64 per XCD)
    const int flat = blockIdx.x;
    const int lg = (flat & 7) * 64 + (flat >> 3);
    const int qx = lg & 15;
    const int ks = (lg >> 4) & 3;
    const int b  = lg >> 6;

    const int rbase = b * SEQ;
    const int kbase = rbase + ks * (SEQ / 4);
    const int qw = qx * 256 + wave * 64;

    float* __restrict__ nump = (ks == 0) ? num0 : (ks == 1) ? num1 : (ks == 2) ? num2 : num3;
    float* __restrict__ denp = (ks == 0) ? den0 : (ks == 1) ? den1 : (ks == 2) ? den2 : den3;

    // persistent Q B-frags: lane n=q=lane&15, k=d=quad*8+e (+32 per step)
    bf8 qf[4][2];
    #pragma unroll
    for (int nq = 0; nq < 4; ++nq)
        #pragma unroll
        for (int st = 0; st < 2; ++st)
            qf[nq][st] = *(const bf8*)(qg + (rbase + qw + nq * 16 + m) * HS + st * 32 + quad * 8);

    // K staging: row srow, 32B of d per thread
    const int srow = t >> 2, soff = (t & 3) * 16;
    // V staging: row-pair j0 = 2*jp, 8 d's per thread
    const int jp = t >> 3, dg = t & 7;
    const int j0 = jp * 2;
    const int jj = j0 & 31;
    const int gj = j0 >> 5;
    const int vq = (jj >> 2) & 3;
    const int vh = (jj >> 4) & 1;
    const int vb = (jj & 3) >> 1;
    const int vcol_base = vh * 4 + 2 * vb;
    const int vchunk_l = 4 * gj + vq;

    uint4 kr0, kr1, vr0, vr1;
    auto load_chunk = [&](int c) {
        const short* pk = kg + (kbase + c * 64 + srow) * HS + soff;
        kr0 = *(const uint4*)pk; kr1 = *(const uint4*)(pk + 8);
        const short* pv = vg + (kbase + c * 64 + j0) * HS + dg * 8;
        vr0 = *(const uint4*)pv; vr1 = *(const uint4*)(pv + HS);
    };
    auto write_chunk = [&](int p) {
        *(bf8*)(&kl[p][srow * 72 + soff])     = __builtin_bit_cast(bf8, kr0);
        *(bf8*)(&kl[p][srow * 72 + soff + 8]) = __builtin_bit_cast(bf8, kr1);
        bf8 v0 = __builtin_bit_cast(bf8, vr0), v1 = __builtin_bit_cast(bf8, vr1);
        #pragma unroll
        for (int i = 0; i < 8; ++i) {
            const int d = dg * 8 + i;
            const int chunk = vchunk_l ^ (i ^ dg);     // (d&7)^(d>>3)
            unsigned val = (unsigned short)v0[i] | ((unsigned)(unsigned short)v1[i] << 16);
            *(unsigned*)(&vl[p][d * 64 + chunk * 8 + vcol_base]) = val;
        }
    };

    f4 o[4][4] = {};
    float den[4] = {0.f, 0.f, 0.f, 0.f};

    load_chunk(0); write_chunk(0); __syncthreads();

    const int NCH = SEQ / 4 / 64;   // 16 chunks of 64 keys
    for (int c = 0; c < NCH; ++c) {
        const int p = c & 1;
        if (c + 1 < NCH) load_chunk(c + 1);

        #pragma unroll
        for (int g = 0; g < 2; ++g) {
            bf8 kA0 = *(const bf8*)(&kl[p][(g * 32 + m) * 72 + quad * 8]);
            bf8 kA1 = *(const bf8*)(&kl[p][(g * 32 + m) * 72 + 32 + quad * 8]);
            bf8 kB0 = *(const bf8*)(&kl[p][(g * 32 + 16 + m) * 72 + quad * 8]);
            bf8 kB1 = *(const bf8*)(&kl[p][(g * 32 + 16 + m) * 72 + 32 + quad * 8]);

            bf8 vf[4];
            #pragma unroll
            for (int dt = 0; dt < 4; ++dt) {
                const int row = dt * 16 + m;
                const int key = (m & 7) ^ (2 * dt + (m >> 3));
                const int chunk = (g * 4 + quad) ^ key;
                vf[dt] = *(const bf8*)(&vl[p][row * 64 + chunk * 8]);
            }

            #pragma unroll
            for (int nq = 0; nq < 4; ++nq) {
                f4 sa = {0.f, 0.f, 0.f, 0.f}, sb = {0.f, 0.f, 0.f, 0.f};
                sa = __builtin_amdgcn_mfma_f32_16x16x32_bf16(kA0, qf[nq][0], sa, 0, 0, 0);
                sa = __builtin_amdgcn_mfma_f32_16x16x32_bf16(kA1, qf[nq][1], sa, 0, 0, 0);
                sb = __builtin_amdgcn_mfma_f32_16x16x32_bf16(kB0, qf[nq][0], sb, 0, 0, 0);
                sb = __builtin_amdgcn_mfma_f32_16x16x32_bf16(kB1, qf[nq][1], sb, 0, 0, 0);
                float e0 = EXP2F(sa[0]), e1 = EXP2F(sa[1]), e2 = EXP2F(sa[2]), e3 = EXP2F(sa[3]);
                float e4 = EXP2F(sb[0]), e5 = EXP2F(sb[1]), e6 = EXP2F(sb[2]), e7 = EXP2F(sb[3]);
                den[nq] += ((e0 + e1) + (e2 + e3)) + ((e4 + e5) + (e6 + e7));
                uint4 pu;
                pu.x = pk2(e0, e1); pu.y = pk2(e2, e3);
                pu.z = pk2(e4, e5); pu.w = pk2(e6, e7);
                bf8 pf = __builtin_bit_cast(bf8, pu);
                #pragma unroll
                for (int dt = 0; dt < 4; ++dt)
                    o[nq][dt] = __builtin_amdgcn_mfma_f32_16x16x32_bf16(vf[dt], pf, o[nq][dt], 0, 0, 0);
            }
        }

        if (c + 1 < NCH) { write_chunk((c + 1) & 1); __syncthreads(); }
    }

    // epilogue: O^T frag row=d=dt*16+quad*4+r, col=q=lane&15. Partial sums out.
    #pragma unroll
    for (int nq = 0; nq < 4; ++nq) {
        float d = den[nq];
        d += __shfl_xor(d, 16, 64);
        d += __shfl_xor(d, 32, 64);
        const int orow = rbase + qw + nq * 16 + m;
        if (quad == 0) denp[orow] = d;
        #pragma unroll
        for (int dt = 0; dt < 4; ++dt)
            *(f4*)(nump + orow * HS + dt * 16 + quad * 4) = o[nq][dt];
    }
}

// ---------------------------------------------------------------------------
// Kernel 3: combine the four key-splits: out = sum(num_i)/sum(den_i).
// ---------------------------------------------------------------------------
__global__ __launch_bounds__(256) void reduce_kernel(
    float* __restrict__ out, const float* __restrict__ num1,
    const float* __restrict__ num2, const float* __restrict__ num3,
    const float* __restrict__ den0, const float* __restrict__ den1,
    const float* __restrict__ den2, const float* __restrict__ den3)
{
    const int gid = blockIdx.x * 256 + threadIdx.x;
    const int base = gid * 4;
    const int r = base >> 6;
    f4 n0 = *(const f4*)(out + base);
    f4 n1 = *(const f4*)(num1 + base);
    f4 n2 = *(const f4*)(num2 + base);
    f4 n3 = *(const f4*)(num3 + base);
    const float rs = 1.0f / ((den0[r] + den1[r]) + (den2[r] + den3[r]));
    f4 res;
    #pragma unroll
    for (int i = 0; i < 4; ++i) res[i] = ((n0[i] + n1[i]) + (n2[i] + n3[i])) * rs;
    *(f4*)(out + base) = res;
}

extern "C" void kernel_launch(void* const* d_in, const int* in_sizes, int n_in,
                              void* d_out, int out_size, void* d_ws, size_t ws_size,
                              hipStream_t stream) {
    const float* ix = (const float*)d_in[0];
    const float* Wk = (const float*)d_in[1];
    const float* Wq = (const float*)d_in[2];
    const float* Wv = (const float*)d_in[3];
    float* out = (float*)d_out;

    const size_t NQKV = (size_t)NBATCH * SEQ * HS;      // 2,097,152 elements
    short* qg = (short*)d_ws;
    short* kg = qg + NQKV;
    short* vg = kg + NQKV;
    short* wt3 = vg + NQKV;                             // 24*192*32 = 147456 shorts
    char*  fbase = (char*)(wt3 + 24 * 192 * 32);        // 16B-aligned
    float* num1 = (float*)fbase;
    float* num2 = num1 + NQKV;
    float* num3 = num2 + NQKV;
    float* den0 = num3 + NQKV;
    float* den1 = den0 + (size_t)NBATCH * SEQ;
    float* den2 = den1 + (size_t)NBATCH * SEQ;
    float* den3 = den2 + (size_t)NBATCH * SEQ;

    wconv_kernel<<<(3 * D_DIM * HS) / 256, 256, 0, stream>>>(Wk, Wq, Wv, wt3);
    proj_kernel<<<(NBATCH * SEQ) / 32, 256, 0, stream>>>(ix, wt3, qg, kg, vg);
    attn_kernel<<<512, 256, 0, stream>>>(qg, kg, vg, out, num1, num2, num3,
                                         den0, den1, den2, den3);
    reduce_kernel<<<(int)(NQKV / (256 * 4)), 256, 0, stream>>>(
        out, num1, num2, num3, den0, den1, den2, den3);
}